// Round 11
// baseline (291.312 us; speedup 1.0000x reference)
//
#include <hip/hip_runtime.h>
#include <stdint.h>

#define AS1 __attribute__((address_space(1)))
#define AS3 __attribute__((address_space(3)))

typedef __bf16 bf16x8 __attribute__((ext_vector_type(8)));
typedef float  f32x4  __attribute__((ext_vector_type(4)));

static constexpr int NODES  = 50000;
static constexpr int EDGES  = 800000;
static constexpr int INDIM  = 512;
static constexpr int HIDDIM = 256;
static constexpr int NB_SCAN = (NODES + 255) / 256;   // 196
static constexpr int AGG_BLOCKS = NODES / 4;          // 12500 (exact)
static constexpr int RED_BLOCKS = 64;
static constexpr int GEMM_MB256 = (NODES + 255) / 256; // 196 row-blocks (BM=256)

// ---------------- ws layout (bytes) ----------------
static constexpr size_t OFF_PART = 0;            // f32  [12500][256]
static constexpr size_t OFF_HN   = 51200000;     // fp8  [50000][256] pre-scaled h (both layers)
static constexpr size_t OFF_H1P  = 76800000;     // fp8  x8 [50000][512] THEN h1p8 [50000][256]
static constexpr size_t OFF_W1T  = 102400000;    // fp8  [256][512]
static constexpr size_t OFF_W2T  = 102662144;    // fp8  [256][256]
static constexpr size_t OFF_DEG  = 102793216;    // i32 [50000]
static constexpr size_t OFF_FILL = 102993216;    // i32 [50000]
static constexpr size_t OFF_ROWP = 103193216;    // i32 [50001]
static constexpr size_t OFF_CSR  = 103393280;    // i32 [800000]
static constexpr size_t OFF_BSUM = 106593280;    // i32 [196]
static constexpr size_t OFF_BOFF = 106594304;    // i32 [256]
static constexpr size_t OFF_P2   = 106595840;    // f32 [64][256]
static constexpr size_t OFF_DINV = 106661376;    // f32 [50000]

__device__ __forceinline__ unsigned char f2fp8(float f) {
  int p = __builtin_amdgcn_cvt_pk_fp8_f32(f, f, 0, false);   // OCP e4m3fn
  return (unsigned char)(p & 0xff);
}
__device__ __forceinline__ void acc_fp8(float4& a, unsigned u) {
  a.x += __builtin_amdgcn_cvt_f32_fp8(u, 0);
  a.y += __builtin_amdgcn_cvt_f32_fp8(u, 1);
  a.z += __builtin_amdgcn_cvt_f32_fp8(u, 2);
  a.w += __builtin_amdgcn_cvt_f32_fp8(u, 3);
}
__device__ __forceinline__ void gload_lds8(const unsigned char* g, unsigned char* l) {
  __builtin_amdgcn_global_load_lds((const AS1 void*)g, (AS3 void*)l, 16, 0, 0);
}
// 8 packed fp8 -> bf16x8 fragment (scalar cvt_f32_fp8 x8 + v_cvt_pk_bf16_f32 x4)
__device__ __forceinline__ bf16x8 fp8x8_to_bf16x8(unsigned long long v) {
  unsigned lo = (unsigned)v, hi = (unsigned)(v >> 32);
  float f0 = __builtin_amdgcn_cvt_f32_fp8(lo, 0), f1 = __builtin_amdgcn_cvt_f32_fp8(lo, 1);
  float f2 = __builtin_amdgcn_cvt_f32_fp8(lo, 2), f3 = __builtin_amdgcn_cvt_f32_fp8(lo, 3);
  float f4 = __builtin_amdgcn_cvt_f32_fp8(hi, 0), f5 = __builtin_amdgcn_cvt_f32_fp8(hi, 1);
  float f6 = __builtin_amdgcn_cvt_f32_fp8(hi, 2), f7 = __builtin_amdgcn_cvt_f32_fp8(hi, 3);
  unsigned r0, r1, r2, r3;
  asm("v_cvt_pk_bf16_f32 %0, %1, %2" : "=v"(r0) : "v"(f0), "v"(f1));
  asm("v_cvt_pk_bf16_f32 %0, %1, %2" : "=v"(r1) : "v"(f2), "v"(f3));
  asm("v_cvt_pk_bf16_f32 %0, %1, %2" : "=v"(r2) : "v"(f4), "v"(f5));
  asm("v_cvt_pk_bf16_f32 %0, %1, %2" : "=v"(r3) : "v"(f6), "v"(f7));
  uint4 u{r0, r1, r2, r3};
  return __builtin_bit_cast(bf16x8, u);
}

// counted-wait primitives (T4)
#define WAITVM(N)  asm volatile("s_waitcnt vmcnt(" #N ")" ::: "memory")
#define HWBARRIER  { asm volatile("" ::: "memory"); __builtin_amdgcn_s_barrier(); \
                     asm volatile("" ::: "memory"); }

// ---------------- x -> fp8 (one pass) ----------------
__global__ __launch_bounds__(256) void convx8_kernel(const float* __restrict__ x,
                                                     unsigned char* __restrict__ x8) {
  size_t i = (size_t)(blockIdx.x * 256 + threadIdx.x) * 8;   // 12500*256*8 exact
  float4 v0 = *(const float4*)(x + i);
  float4 v1 = *(const float4*)(x + i + 4);
  int p0 = __builtin_amdgcn_cvt_pk_fp8_f32(v0.x, v0.y, 0, false);
  p0     = __builtin_amdgcn_cvt_pk_fp8_f32(v0.z, v0.w, p0, true);
  int p1 = __builtin_amdgcn_cvt_pk_fp8_f32(v1.x, v1.y, 0, false);
  p1     = __builtin_amdgcn_cvt_pk_fp8_f32(v1.z, v1.w, p1, true);
  *(uint2*)(x8 + i) = uint2{(unsigned)p0, (unsigned)p1};
}

// ---------------- weight transpose + fp8 + scratch zeroing (fused) ----------------
__global__ __launch_bounds__(256) void transw8_zero_kernel(const float* __restrict__ W1,
                                                           const float* __restrict__ W2,
                                                           unsigned char* __restrict__ W1T8,
                                                           unsigned char* __restrict__ W2T8,
                                                           int4* __restrict__ zreg) {
  int b = blockIdx.x, tid = threadIdx.x;
  if (b < 512) {                                    // W1T8[n][k] = fp8(W1[k][n])
    int t = b * 256 + tid; int n = t >> 9, k = t & 511;
    W1T8[t] = f2fp8(W1[k * HIDDIM + n]);
  } else if (b < 768) {
    int u = (b - 512) * 256 + tid; int n = u >> 8, k = u & 255;
    W2T8[u] = f2fp8(W2[k * HIDDIM + n]);
  } else {                                          // zero deg+fill (400000 B)
    int i = (b - 768) * 256 + tid;
    if (i < 25000) zreg[i] = int4{0, 0, 0, 0};
  }
}

// ---------------- degree histogram (inline int64-layout detect) ----------------
__global__ __launch_bounds__(256) void hist_kernel(const int* __restrict__ ei,
                                                   int* __restrict__ deg) {
  __shared__ int sflag;
  if (threadIdx.x < 64) {
    unsigned long long b = __ballot(ei[2 * threadIdx.x + 1] == 0);
    if (threadIdx.x == 0) sflag = (b == 0xFFFFFFFFFFFFFFFFull) ? 1 : 0;
  }
  __syncthreads();
  int f = sflag;
  int e = blockIdx.x * 256 + threadIdx.x;        // 3125*256 = 800000 exact
  int d = f ? ei[2 * (EDGES + e)] : ei[EDGES + e];
  atomicAdd(&deg[d], 1);
}

// ---------------- scan (3 kernels) + dinv ----------------
__global__ __launch_bounds__(256) void scan1_kernel(const int* __restrict__ deg,
                                                    int* __restrict__ rowptr,
                                                    int* __restrict__ bsum,
                                                    float* __restrict__ dinv) {
  __shared__ int s[256];
  int t = threadIdx.x, i = blockIdx.x * 256 + t;
  int v = (i < NODES) ? deg[i] : 0;
  if (i < NODES) dinv[i] = rsqrtf((float)(v + 1));   // +1 self-loop
  s[t] = v; __syncthreads();
  for (int off = 1; off < 256; off <<= 1) {
    int x = (t >= off) ? s[t - off] : 0;
    __syncthreads(); s[t] += x; __syncthreads();
  }
  if (i < NODES) rowptr[i] = s[t] - v;
  if (t == 255) bsum[blockIdx.x] = s[255];
}
__global__ __launch_bounds__(256) void scan2_kernel(const int* __restrict__ bsum,
                                                    int* __restrict__ boff,
                                                    int* __restrict__ rowptrN) {
  __shared__ int s[256];
  int t = threadIdx.x;
  int v = (t < NB_SCAN) ? bsum[t] : 0;
  s[t] = v; __syncthreads();
  for (int off = 1; off < 256; off <<= 1) {
    int x = (t >= off) ? s[t - off] : 0;
    __syncthreads(); s[t] += x; __syncthreads();
  }
  if (t < NB_SCAN) boff[t] = s[t] - v;
  if (t == 255) *rowptrN = s[255];
}
__global__ __launch_bounds__(256) void scan3_kernel(int* __restrict__ rowptr,
                                                    const int* __restrict__ boff) {
  int i = blockIdx.x * 256 + threadIdx.x;
  if (i < NODES) rowptr[i] += boff[blockIdx.x];
}

// ---------------- CSR fill (inline detect) ----------------
__global__ __launch_bounds__(256) void fill_kernel(const int* __restrict__ ei,
                                                   const int* __restrict__ rowptr,
                                                   int* __restrict__ fill,
                                                   int* __restrict__ csr) {
  __shared__ int sflag;
  if (threadIdx.x < 64) {
    unsigned long long b = __ballot(ei[2 * threadIdx.x + 1] == 0);
    if (threadIdx.x == 0) sflag = (b == 0xFFFFFFFFFFFFFFFFull) ? 1 : 0;
  }
  __syncthreads();
  int f = sflag;
  int e = blockIdx.x * 256 + threadIdx.x;
  int s, d;
  if (f) { s = ei[2 * e]; d = ei[2 * (EDGES + e)]; }
  else   { s = ei[e];     d = ei[EDGES + e]; }
  int p = atomicAdd(&fill[d], 1);
  csr[rowptr[d] + p] = s;
}

// ---------------- GEMM: fp8 memory, bf16 MFMA. BM=BN=256, BK=64, counted vmcnt ----
// All staging via global_load_lds of fp8 (16B chunks, chunk^(row&3) swizzle on both
// source and read side - G21). Per-step chip-wide service only 6.3MB (was 15.7).
// Fragments: ds_read b64 (8 fp8) -> cvt to bf16x8 in-reg -> verified bf16 MFMA.
template<int K>
__global__ __launch_bounds__(512, 2) void gemm_fp8_kernel(const unsigned char* __restrict__ A8,
                                                          const unsigned char* __restrict__ BT8,
                                                          const float* __restrict__ dinv,
                                                          unsigned char* __restrict__ Cn8) {
  constexpr int NSTEP = K / 64;
  __shared__ unsigned char As[2][256 * 64];    // 16 KB per buf
  __shared__ unsigned char Bs[2][256 * 64];    // 16 KB per buf (total 64 KB)
  const int tid = threadIdx.x, wave = tid >> 6, lane = tid & 63;
  const int fr = lane & 15, q = lane >> 4;
  const int wr = wave >> 2, wc = wave & 3;     // 2m x 4n
  const int m0 = blockIdx.x * 256;

  // staging lane geometry: 16 rows per 1KB chunk-pair; lane covers (row l>>2, chunk l&3)
  const int srl0 = lane >> 2, sch = lane & 3;

  f32x4 acc[8][4] = {};

#define STAGE_T(dstArr, buf, srcp, rowbase, kb, CLAMP)                        \
  {                                                                           \
    _Pragma("unroll")                                                         \
    for (int c = 0; c < 2; ++c) {                                             \
      int rl = (wave * 2 + c) * 16 + srl0;                                    \
      int gr = (rowbase) + rl;                                                \
      if (CLAMP) { if (gr > NODES - 1) gr = NODES - 1; }                      \
      const unsigned char* sp = srcp + (size_t)gr * K + (kb) +                \
                                ((sch ^ (rl & 3)) << 4);                      \
      gload_lds8(sp, &dstArr[buf][(wave * 2 + c) * 1024]);                    \
    }                                                                         \
  }

  // ---- prologue: tile 0 into buf 0 ----
  STAGE_T(As, 0, A8, m0, 0, true);
  STAGE_T(Bs, 0, BT8, 0, 0, false);

  for (int t = 0; t < NSTEP; ++t) {
    const int cur = t & 1, nxt = cur ^ 1;
    if (t + 1 < NSTEP) {
      const int kb1 = (t + 1) * 64;
      STAGE_T(As, nxt, A8, m0, kb1, true);
      STAGE_T(Bs, nxt, BT8, 0, kb1, false);
      WAITVM(4);                                // wait tile-t only; t+1 in flight
    } else {
      WAITVM(0);
    }
    HWBARRIER;

#pragma unroll
    for (int s = 0; s < 2; ++s) {               // two K=32 slabs per step
      bf16x8 af[8], bq[4];
#pragma unroll
      for (int m = 0; m < 8; ++m) {
        int row = wr * 128 + m * 16 + fr;
        int cch = s * 2 + (q >> 1);
        unsigned long long v = *(const unsigned long long*)
            &As[cur][row * 64 + ((cch ^ (row & 3)) << 4) + (q & 1) * 8];
        af[m] = fp8x8_to_bf16x8(v);
      }
#pragma unroll
      for (int n = 0; n < 4; ++n) {
        int row = wc * 64 + n * 16 + fr;
        int cch = s * 2 + (q >> 1);
        unsigned long long v = *(const unsigned long long*)
            &Bs[cur][row * 64 + ((cch ^ (row & 3)) << 4) + (q & 1) * 8];
        bq[n] = fp8x8_to_bf16x8(v);
      }
#pragma unroll
      for (int m = 0; m < 8; ++m)
#pragma unroll
        for (int n = 0; n < 4; ++n)
          acc[m][n] = __builtin_amdgcn_mfma_f32_16x16x32_bf16(af[m], bq[n], acc[m][n], 0, 0, 0);
    }
    HWBARRIER;
  }
#undef STAGE_T

  // epilogue: C/D layout col=lane&15, row=q*4+reg ; write fp8 with dinv scale
  const int rq = q * 4;
#pragma unroll
  for (int m = 0; m < 8; ++m) {
    int rbase = m0 + wr * 128 + m * 16 + rq;
#pragma unroll
    for (int r = 0; r < 4; ++r) {
      int grow = rbase + r;
      if (grow < NODES) {
        float dv = dinv[grow];
#pragma unroll
        for (int n = 0; n < 4; ++n) {
          int gcol = wc * 64 + n * 16 + fr;
          Cn8[(size_t)grow * 256 + gcol] = f2fp8(acc[m][n][r] * dv);
        }
      }
    }
  }
}

// ---------------- gather core: fp8 rows, unroll-8 ----------------
__device__ __forceinline__ float4 gather_node(const unsigned char* __restrict__ hn8,
                                              const int* __restrict__ rowptr,
                                              const int* __restrict__ csr,
                                              int node, int boff) {
  float4 A{0.f, 0.f, 0.f, 0.f}, B{0.f, 0.f, 0.f, 0.f};
  unsigned us = *(const unsigned*)(hn8 + (size_t)node * 256 + boff);   // self-loop
  acc_fp8(A, us);
  int e0 = rowptr[node], e1 = rowptr[node + 1];
  int e = e0;
  for (; e + 8 <= e1; e += 8) {
    unsigned u0 = *(const unsigned*)(hn8 + (size_t)csr[e + 0] * 256 + boff);
    unsigned u1 = *(const unsigned*)(hn8 + (size_t)csr[e + 1] * 256 + boff);
    unsigned u2 = *(const unsigned*)(hn8 + (size_t)csr[e + 2] * 256 + boff);
    unsigned u3 = *(const unsigned*)(hn8 + (size_t)csr[e + 3] * 256 + boff);
    unsigned u4 = *(const unsigned*)(hn8 + (size_t)csr[e + 4] * 256 + boff);
    unsigned u5 = *(const unsigned*)(hn8 + (size_t)csr[e + 5] * 256 + boff);
    unsigned u6 = *(const unsigned*)(hn8 + (size_t)csr[e + 6] * 256 + boff);
    unsigned u7 = *(const unsigned*)(hn8 + (size_t)csr[e + 7] * 256 + boff);
    acc_fp8(A, u0); acc_fp8(B, u1); acc_fp8(A, u2); acc_fp8(B, u3);
    acc_fp8(A, u4); acc_fp8(B, u5); acc_fp8(A, u6); acc_fp8(B, u7);
  }
  for (; e + 4 <= e1; e += 4) {
    unsigned u0 = *(const unsigned*)(hn8 + (size_t)csr[e + 0] * 256 + boff);
    unsigned u1 = *(const unsigned*)(hn8 + (size_t)csr[e + 1] * 256 + boff);
    unsigned u2 = *(const unsigned*)(hn8 + (size_t)csr[e + 2] * 256 + boff);
    unsigned u3 = *(const unsigned*)(hn8 + (size_t)csr[e + 3] * 256 + boff);
    acc_fp8(A, u0); acc_fp8(B, u1); acc_fp8(A, u2); acc_fp8(B, u3);
  }
  for (; e < e1; ++e) {
    unsigned u = *(const unsigned*)(hn8 + (size_t)csr[e] * 256 + boff);
    acc_fp8(A, u);
  }
  return float4{A.x + B.x, A.y + B.y, A.z + B.z, A.w + B.w};
}

// ---------------- aggregation: wave per node; agg1 writes fp8 ----------------
__global__ __launch_bounds__(256) void agg1_kernel(const unsigned char* __restrict__ hn8,
                                                   const float* __restrict__ dinv,
                                                   const int* __restrict__ rowptr,
                                                   const int* __restrict__ csr,
                                                   const float* __restrict__ bias,
                                                   unsigned char* __restrict__ h1p8) {
  int wave = threadIdx.x >> 6, lane = threadIdx.x & 63;
  int node = blockIdx.x * 4 + wave;
  int c0 = lane * 4;
  float4 a = gather_node(hn8, rowptr, csr, node, c0);
  float di = dinv[node];
  float4 b = *(const float4*)(bias + c0);
  float r0 = fmaxf(fmaf(di, a.x, b.x), 0.f);
  float r1 = fmaxf(fmaf(di, a.y, b.y), 0.f);
  float r2 = fmaxf(fmaf(di, a.z, b.z), 0.f);
  float r3 = fmaxf(fmaf(di, a.w, b.w), 0.f);
  int p = __builtin_amdgcn_cvt_pk_fp8_f32(r0, r1, 0, false);
  p     = __builtin_amdgcn_cvt_pk_fp8_f32(r2, r3, p, true);
  *(unsigned*)(h1p8 + (size_t)node * 256 + c0) = (unsigned)p;
}

__global__ __launch_bounds__(256) void agg2_kernel(const unsigned char* __restrict__ hn8,
                                                   const float* __restrict__ dinv,
                                                   const int* __restrict__ rowptr,
                                                   const int* __restrict__ csr,
                                                   const float* __restrict__ bias,
                                                   float* __restrict__ partials) {
  __shared__ float sm[1024];
  int wave = threadIdx.x >> 6, lane = threadIdx.x & 63;
  int node = blockIdx.x * 4 + wave;                 // 12500*4 = 50000 exact
  int c0 = lane * 4;
  float4 a = gather_node(hn8, rowptr, csr, node, c0);
  float di = dinv[node];
  float4 b = *(const float4*)(bias + c0);
  sm[wave * 256 + c0 + 0] = fmaxf(fmaf(di, a.x, b.x), 0.f);
  sm[wave * 256 + c0 + 1] = fmaxf(fmaf(di, a.y, b.y), 0.f);
  sm[wave * 256 + c0 + 2] = fmaxf(fmaf(di, a.z, b.z), 0.f);
  sm[wave * 256 + c0 + 3] = fmaxf(fmaf(di, a.w, b.w), 0.f);
  __syncthreads();
  int t = threadIdx.x;
  partials[(size_t)blockIdx.x * 256 + t] = sm[t] + sm[256 + t] + sm[512 + t] + sm[768 + t];
}

// ---------------- readout ----------------
__global__ __launch_bounds__(256) void reduce2_kernel(const float* __restrict__ partials,
                                                      float* __restrict__ p2) {
  int t = threadIdx.x, b = blockIdx.x;              // 64 blocks
  float s = 0.f;
  for (int r = b; r < AGG_BLOCKS; r += RED_BLOCKS) s += partials[(size_t)r * 256 + t];
  p2[b * 256 + t] = s;
}
__global__ __launch_bounds__(256) void final_kernel(const float* __restrict__ p2,
                                                    const float* __restrict__ Wfc,
                                                    const float* __restrict__ bfc,
                                                    float* __restrict__ out) {
  __shared__ float red[256];
  int t = threadIdx.x;
  float s = 0.f;
  for (int b = 0; b < RED_BLOCKS; ++b) s += p2[b * 256 + t];
  float g = s * (1.0f / (float)NODES);
  red[t] = g * Wfc[t];
  __syncthreads();
  for (int off = 128; off > 0; off >>= 1) {
    if (t < off) red[t] += red[t + off];
    __syncthreads();
  }
  if (t == 0) {
    float z = red[0] + bfc[0];
    out[0] = 1.0f / (1.0f + expf(-z));
  }
}

// ---------------- launch ----------------
extern "C" void kernel_launch(void* const* d_in, const int* in_sizes, int n_in,
                              void* d_out, int out_size, void* d_ws, size_t ws_size,
                              hipStream_t stream) {
  (void)in_sizes; (void)n_in; (void)out_size; (void)ws_size;
  const float* x   = (const float*)d_in[0];
  const int*   ei  = (const int*)d_in[1];
  const float* W1  = (const float*)d_in[2];
  const float* b1  = (const float*)d_in[3];
  const float* W2  = (const float*)d_in[4];
  const float* b2  = (const float*)d_in[5];
  const float* Wfc = (const float*)d_in[6];
  const float* bfc = (const float*)d_in[7];
  float* out = (float*)d_out;
  char* ws = (char*)d_ws;

  unsigned char*  hn8  = (unsigned char*)(ws + OFF_HN);
  unsigned char*  x8   = (unsigned char*)(ws + OFF_H1P);   // x8 aliases h1p region
  unsigned char*  h1p8 = (unsigned char*)(ws + OFF_H1P);   // written after gemm1
  unsigned char*  w1t8 = (unsigned char*)(ws + OFF_W1T);
  unsigned char*  w2t8 = (unsigned char*)(ws + OFF_W2T);
  int*   deg    = (int*)(ws + OFF_DEG);
  int*   fill   = (int*)(ws + OFF_FILL);
  int*   rowptr = (int*)(ws + OFF_ROWP);
  int*   csr    = (int*)(ws + OFF_CSR);
  int*   bsum   = (int*)(ws + OFF_BSUM);
  int*   boff   = (int*)(ws + OFF_BOFF);
  float* part   = (float*)(ws + OFF_PART);
  float* p2     = (float*)(ws + OFF_P2);
  float* dinv   = (float*)(ws + OFF_DINV);

  transw8_zero_kernel<<<866, 256, 0, stream>>>(W1, W2, w1t8, w2t8, (int4*)deg);
  hist_kernel<<<EDGES / 256, 256, 0, stream>>>(ei, deg);
  scan1_kernel<<<NB_SCAN, 256, 0, stream>>>(deg, rowptr, bsum, dinv);
  scan2_kernel<<<1, 256, 0, stream>>>(bsum, boff, rowptr + NODES);
  scan3_kernel<<<NB_SCAN, 256, 0, stream>>>(rowptr, boff);
  fill_kernel<<<EDGES / 256, 256, 0, stream>>>(ei, rowptr, fill, csr);
  convx8_kernel<<<NODES * INDIM / (256 * 8), 256, 0, stream>>>(x, x8);

  gemm_fp8_kernel<INDIM><<<GEMM_MB256, 512, 0, stream>>>(x8, w1t8, dinv, hn8);
  agg1_kernel<<<AGG_BLOCKS, 256, 0, stream>>>(hn8, dinv, rowptr, csr, b1, h1p8);
  gemm_fp8_kernel<HIDDIM><<<GEMM_MB256, 512, 0, stream>>>(h1p8, w2t8, dinv, hn8);
  agg2_kernel<<<AGG_BLOCKS, 256, 0, stream>>>(hn8, dinv, rowptr, csr, b2, part);
  reduce2_kernel<<<RED_BLOCKS, 256, 0, stream>>>(part, p2);
  final_kernel<<<1, 256, 0, stream>>>(p2, Wfc, bfc, out);
}

// Round 12
// 284.390 us; speedup vs baseline: 1.0243x; 1.0243x over previous
//
#include <hip/hip_runtime.h>
#include <stdint.h>

#define AS1 __attribute__((address_space(1)))
#define AS3 __attribute__((address_space(3)))

typedef float f32x4 __attribute__((ext_vector_type(4)));

static constexpr int NODES  = 50000;
static constexpr int EDGES  = 800000;
static constexpr int INDIM  = 512;
static constexpr int HIDDIM = 256;
static constexpr int NB_SCAN = (NODES + 255) / 256;   // 196
static constexpr int AGG_BLOCKS = NODES / 4;          // 12500 (exact)
static constexpr int RED_BLOCKS = 64;
static constexpr int GEMM_MB256 = (NODES + 255) / 256; // 196 row-blocks (BM=256)

// ---------------- ws layout (bytes) ----------------
static constexpr size_t OFF_PART = 0;            // f32  [12500][256]
static constexpr size_t OFF_HN   = 51200000;     // fp8  [50000][256] pre-scaled h (both layers)
static constexpr size_t OFF_H1P  = 76800000;     // fp8  x8 [50000][512] THEN h1p8 [50000][256]
static constexpr size_t OFF_W1T  = 102400000;    // fp8  [256][512]
static constexpr size_t OFF_W2T  = 102662144;    // fp8  [256][256]
static constexpr size_t OFF_DEG  = 102793216;    // i32 [50000]
static constexpr size_t OFF_FILL = 102993216;    // i32 [50000]
static constexpr size_t OFF_ROWP = 103193216;    // i32 [50001]
static constexpr size_t OFF_CSR  = 103393280;    // i32 [800000]
static constexpr size_t OFF_BSUM = 106593280;    // i32 [196]
static constexpr size_t OFF_BOFF = 106594304;    // i32 [256]
static constexpr size_t OFF_P2   = 106595840;    // f32 [64][256]
static constexpr size_t OFF_DINV = 106661376;    // f32 [50000]

__device__ __forceinline__ unsigned char f2fp8(float f) {
  int p = __builtin_amdgcn_cvt_pk_fp8_f32(f, f, 0, false);   // OCP e4m3fn
  return (unsigned char)(p & 0xff);
}
__device__ __forceinline__ void acc_fp8(float4& a, unsigned u) {
  a.x += __builtin_amdgcn_cvt_f32_fp8(u, 0);
  a.y += __builtin_amdgcn_cvt_f32_fp8(u, 1);
  a.z += __builtin_amdgcn_cvt_f32_fp8(u, 2);
  a.w += __builtin_amdgcn_cvt_f32_fp8(u, 3);
}
__device__ __forceinline__ void gload_lds8(const unsigned char* g, unsigned char* l) {
  __builtin_amdgcn_global_load_lds((const AS1 void*)g, (AS3 void*)l, 16, 0, 0);
}

// counted-wait primitives (T4)
#define WAITVM(N)  asm volatile("s_waitcnt vmcnt(" #N ")" ::: "memory")
#define HWBARRIER  { asm volatile("" ::: "memory"); __builtin_amdgcn_s_barrier(); \
                     asm volatile("" ::: "memory"); }

// ---------------- x -> fp8 (one pass) ----------------
__global__ __launch_bounds__(256) void convx8_kernel(const float* __restrict__ x,
                                                     unsigned char* __restrict__ x8) {
  size_t i = (size_t)(blockIdx.x * 256 + threadIdx.x) * 8;   // 12500*256*8 exact
  float4 v0 = *(const float4*)(x + i);
  float4 v1 = *(const float4*)(x + i + 4);
  int p0 = __builtin_amdgcn_cvt_pk_fp8_f32(v0.x, v0.y, 0, false);
  p0     = __builtin_amdgcn_cvt_pk_fp8_f32(v0.z, v0.w, p0, true);
  int p1 = __builtin_amdgcn_cvt_pk_fp8_f32(v1.x, v1.y, 0, false);
  p1     = __builtin_amdgcn_cvt_pk_fp8_f32(v1.z, v1.w, p1, true);
  *(uint2*)(x8 + i) = uint2{(unsigned)p0, (unsigned)p1};
}

// ---------------- weight transpose + fp8 + scratch zeroing (fused) ----------------
__global__ __launch_bounds__(256) void transw8_zero_kernel(const float* __restrict__ W1,
                                                           const float* __restrict__ W2,
                                                           unsigned char* __restrict__ W1T8,
                                                           unsigned char* __restrict__ W2T8,
                                                           int4* __restrict__ zreg) {
  int b = blockIdx.x, tid = threadIdx.x;
  if (b < 512) {                                    // W1T8[n][k] = fp8(W1[k][n])
    int t = b * 256 + tid; int n = t >> 9, k = t & 511;
    W1T8[t] = f2fp8(W1[k * HIDDIM + n]);
  } else if (b < 768) {
    int u = (b - 512) * 256 + tid; int n = u >> 8, k = u & 255;
    W2T8[u] = f2fp8(W2[k * HIDDIM + n]);
  } else {                                          // zero deg+fill (400000 B)
    int i = (b - 768) * 256 + tid;
    if (i < 25000) zreg[i] = int4{0, 0, 0, 0};
  }
}

// ---------------- degree histogram (inline int64-layout detect) ----------------
__global__ __launch_bounds__(256) void hist_kernel(const int* __restrict__ ei,
                                                   int* __restrict__ deg) {
  __shared__ int sflag;
  if (threadIdx.x < 64) {
    unsigned long long b = __ballot(ei[2 * threadIdx.x + 1] == 0);
    if (threadIdx.x == 0) sflag = (b == 0xFFFFFFFFFFFFFFFFull) ? 1 : 0;
  }
  __syncthreads();
  int f = sflag;
  int e = blockIdx.x * 256 + threadIdx.x;        // 3125*256 = 800000 exact
  int d = f ? ei[2 * (EDGES + e)] : ei[EDGES + e];
  atomicAdd(&deg[d], 1);
}

// ---------------- scan (3 kernels) + dinv ----------------
__global__ __launch_bounds__(256) void scan1_kernel(const int* __restrict__ deg,
                                                    int* __restrict__ rowptr,
                                                    int* __restrict__ bsum,
                                                    float* __restrict__ dinv) {
  __shared__ int s[256];
  int t = threadIdx.x, i = blockIdx.x * 256 + t;
  int v = (i < NODES) ? deg[i] : 0;
  if (i < NODES) dinv[i] = rsqrtf((float)(v + 1));   // +1 self-loop
  s[t] = v; __syncthreads();
  for (int off = 1; off < 256; off <<= 1) {
    int x = (t >= off) ? s[t - off] : 0;
    __syncthreads(); s[t] += x; __syncthreads();
  }
  if (i < NODES) rowptr[i] = s[t] - v;
  if (t == 255) bsum[blockIdx.x] = s[255];
}
__global__ __launch_bounds__(256) void scan2_kernel(const int* __restrict__ bsum,
                                                    int* __restrict__ boff,
                                                    int* __restrict__ rowptrN) {
  __shared__ int s[256];
  int t = threadIdx.x;
  int v = (t < NB_SCAN) ? bsum[t] : 0;
  s[t] = v; __syncthreads();
  for (int off = 1; off < 256; off <<= 1) {
    int x = (t >= off) ? s[t - off] : 0;
    __syncthreads(); s[t] += x; __syncthreads();
  }
  if (t < NB_SCAN) boff[t] = s[t] - v;
  if (t == 255) *rowptrN = s[255];
}
__global__ __launch_bounds__(256) void scan3_kernel(int* __restrict__ rowptr,
                                                    const int* __restrict__ boff) {
  int i = blockIdx.x * 256 + threadIdx.x;
  if (i < NODES) rowptr[i] += boff[blockIdx.x];
}

// ---------------- CSR fill (inline detect) ----------------
__global__ __launch_bounds__(256) void fill_kernel(const int* __restrict__ ei,
                                                   const int* __restrict__ rowptr,
                                                   int* __restrict__ fill,
                                                   int* __restrict__ csr) {
  __shared__ int sflag;
  if (threadIdx.x < 64) {
    unsigned long long b = __ballot(ei[2 * threadIdx.x + 1] == 0);
    if (threadIdx.x == 0) sflag = (b == 0xFFFFFFFFFFFFFFFFull) ? 1 : 0;
  }
  __syncthreads();
  int f = sflag;
  int e = blockIdx.x * 256 + threadIdx.x;
  int s, d;
  if (f) { s = ei[2 * e]; d = ei[2 * (EDGES + e)]; }
  else   { s = ei[e];     d = ei[EDGES + e]; }
  int p = atomicAdd(&fill[d], 1);
  csr[rowptr[d] + p] = s;
}

// ---------------- GEMM: fp8 memory + NATIVE fp8 MFMA. BM=BN=256, BK=64 ----
// ds_read b64 (8 fp8) IS the 2-VGPR A/B operand of mfma_f32_16x16x32_fp8_fp8 -
// zero conversion VALU (R11's 288 instr/wave/step cvt tax deleted). Fragment
// map mirrors verified bf16 16x16x32 (8 K-contig elems/lane); C/D layout is
// shape-determined (m121-m128). Counted vmcnt keeps next tile in flight.
template<int K>
__global__ __launch_bounds__(512, 2) void gemm_fp8_kernel(const unsigned char* __restrict__ A8,
                                                          const unsigned char* __restrict__ BT8,
                                                          const float* __restrict__ dinv,
                                                          unsigned char* __restrict__ Cn8) {
  constexpr int NSTEP = K / 64;
  __shared__ unsigned char As[2][256 * 64];    // 16 KB per buf
  __shared__ unsigned char Bs[2][256 * 64];    // 16 KB per buf (total 64 KB)
  const int tid = threadIdx.x, wave = tid >> 6, lane = tid & 63;
  const int fr = lane & 15, q = lane >> 4;
  const int wr = wave >> 2, wc = wave & 3;     // 2m x 4n
  const int m0 = blockIdx.x * 256;

  // staging lane geometry: 16-row chunk, lane -> (row lane>>2, 16B grp lane&3)
  const int srl0 = lane >> 2, sch = lane & 3;

  f32x4 acc[8][4] = {};

#define STAGE_T(dstArr, buf, srcp, rowbase, kb, CLAMP)                        \
  {                                                                           \
    _Pragma("unroll")                                                         \
    for (int c = 0; c < 2; ++c) {                                             \
      int rl = (wave * 2 + c) * 16 + srl0;                                    \
      int gr = (rowbase) + rl;                                                \
      if (CLAMP) { if (gr > NODES - 1) gr = NODES - 1; }                      \
      const unsigned char* sp = srcp + (size_t)gr * K + (kb) +                \
                                ((sch ^ (rl & 3)) << 4);                      \
      gload_lds8(sp, &dstArr[buf][(wave * 2 + c) * 1024]);                    \
    }                                                                         \
  }

  // ---- prologue: tile 0 into buf 0 ----
  STAGE_T(As, 0, A8, m0, 0, true);
  STAGE_T(Bs, 0, BT8, 0, 0, false);

  for (int t = 0; t < NSTEP; ++t) {
    const int cur = t & 1, nxt = cur ^ 1;
    if (t + 1 < NSTEP) {
      const int kb1 = (t + 1) * 64;
      STAGE_T(As, nxt, A8, m0, kb1, true);
      STAGE_T(Bs, nxt, BT8, 0, kb1, false);
      WAITVM(4);                                // tile-t done; t+1 in flight
    } else {
      WAITVM(0);
    }
    HWBARRIER;

#pragma unroll
    for (int s = 0; s < 2; ++s) {               // two K=32 slabs per step
      long af[8], bq[4];
#pragma unroll
      for (int m = 0; m < 8; ++m) {
        int row = wr * 128 + m * 16 + fr;
        int cch = s * 2 + (q >> 1);
        af[m] = *(const long*)
            &As[cur][row * 64 + ((cch ^ (row & 3)) << 4) + (q & 1) * 8];
      }
#pragma unroll
      for (int n = 0; n < 4; ++n) {
        int row = wc * 64 + n * 16 + fr;
        int cch = s * 2 + (q >> 1);
        bq[n] = *(const long*)
            &Bs[cur][row * 64 + ((cch ^ (row & 3)) << 4) + (q & 1) * 8];
      }
#pragma unroll
      for (int m = 0; m < 8; ++m)
#pragma unroll
        for (int n = 0; n < 4; ++n)
          acc[m][n] = __builtin_amdgcn_mfma_f32_16x16x32_fp8_fp8(af[m], bq[n], acc[m][n], 0, 0, 0);
    }
    HWBARRIER;
  }
#undef STAGE_T

  // epilogue: C/D layout col=lane&15, row=q*4+reg ; write fp8 with dinv scale
  const int rq = q * 4;
#pragma unroll
  for (int m = 0; m < 8; ++m) {
    int rbase = m0 + wr * 128 + m * 16 + rq;
#pragma unroll
    for (int r = 0; r < 4; ++r) {
      int grow = rbase + r;
      if (grow < NODES) {
        float dv = dinv[grow];
#pragma unroll
        for (int n = 0; n < 4; ++n) {
          int gcol = wc * 64 + n * 16 + fr;
          Cn8[(size_t)grow * 256 + gcol] = f2fp8(acc[m][n][r] * dv);
        }
      }
    }
  }
}

// ---------------- gather core: fp8 rows, unroll-8 ----------------
__device__ __forceinline__ float4 gather_node(const unsigned char* __restrict__ hn8,
                                              const int* __restrict__ rowptr,
                                              const int* __restrict__ csr,
                                              int node, int boff) {
  float4 A{0.f, 0.f, 0.f, 0.f}, B{0.f, 0.f, 0.f, 0.f};
  unsigned us = *(const unsigned*)(hn8 + (size_t)node * 256 + boff);   // self-loop
  acc_fp8(A, us);
  int e0 = rowptr[node], e1 = rowptr[node + 1];
  int e = e0;
  for (; e + 8 <= e1; e += 8) {
    unsigned u0 = *(const unsigned*)(hn8 + (size_t)csr[e + 0] * 256 + boff);
    unsigned u1 = *(const unsigned*)(hn8 + (size_t)csr[e + 1] * 256 + boff);
    unsigned u2 = *(const unsigned*)(hn8 + (size_t)csr[e + 2] * 256 + boff);
    unsigned u3 = *(const unsigned*)(hn8 + (size_t)csr[e + 3] * 256 + boff);
    unsigned u4 = *(const unsigned*)(hn8 + (size_t)csr[e + 4] * 256 + boff);
    unsigned u5 = *(const unsigned*)(hn8 + (size_t)csr[e + 5] * 256 + boff);
    unsigned u6 = *(const unsigned*)(hn8 + (size_t)csr[e + 6] * 256 + boff);
    unsigned u7 = *(const unsigned*)(hn8 + (size_t)csr[e + 7] * 256 + boff);
    acc_fp8(A, u0); acc_fp8(B, u1); acc_fp8(A, u2); acc_fp8(B, u3);
    acc_fp8(A, u4); acc_fp8(B, u5); acc_fp8(A, u6); acc_fp8(B, u7);
  }
  for (; e + 4 <= e1; e += 4) {
    unsigned u0 = *(const unsigned*)(hn8 + (size_t)csr[e + 0] * 256 + boff);
    unsigned u1 = *(const unsigned*)(hn8 + (size_t)csr[e + 1] * 256 + boff);
    unsigned u2 = *(const unsigned*)(hn8 + (size_t)csr[e + 2] * 256 + boff);
    unsigned u3 = *(const unsigned*)(hn8 + (size_t)csr[e + 3] * 256 + boff);
    acc_fp8(A, u0); acc_fp8(B, u1); acc_fp8(A, u2); acc_fp8(B, u3);
  }
  for (; e < e1; ++e) {
    unsigned u = *(const unsigned*)(hn8 + (size_t)csr[e] * 256 + boff);
    acc_fp8(A, u);
  }
  return float4{A.x + B.x, A.y + B.y, A.z + B.z, A.w + B.w};
}

// ---------------- aggregation: wave per node; agg1 writes fp8 ----------------
__global__ __launch_bounds__(256) void agg1_kernel(const unsigned char* __restrict__ hn8,
                                                   const float* __restrict__ dinv,
                                                   const int* __restrict__ rowptr,
                                                   const int* __restrict__ csr,
                                                   const float* __restrict__ bias,
                                                   unsigned char* __restrict__ h1p8) {
  int wave = threadIdx.x >> 6, lane = threadIdx.x & 63;
  int node = blockIdx.x * 4 + wave;
  int c0 = lane * 4;
  float4 a = gather_node(hn8, rowptr, csr, node, c0);
  float di = dinv[node];
  float4 b = *(const float4*)(bias + c0);
  float r0 = fmaxf(fmaf(di, a.x, b.x), 0.f);
  float r1 = fmaxf(fmaf(di, a.y, b.y), 0.f);
  float r2 = fmaxf(fmaf(di, a.z, b.z), 0.f);
  float r3 = fmaxf(fmaf(di, a.w, b.w), 0.f);
  int p = __builtin_amdgcn_cvt_pk_fp8_f32(r0, r1, 0, false);
  p     = __builtin_amdgcn_cvt_pk_fp8_f32(r2, r3, p, true);
  *(unsigned*)(h1p8 + (size_t)node * 256 + c0) = (unsigned)p;
}

__global__ __launch_bounds__(256) void agg2_kernel(const unsigned char* __restrict__ hn8,
                                                   const float* __restrict__ dinv,
                                                   const int* __restrict__ rowptr,
                                                   const int* __restrict__ csr,
                                                   const float* __restrict__ bias,
                                                   float* __restrict__ partials) {
  __shared__ float sm[1024];
  int wave = threadIdx.x >> 6, lane = threadIdx.x & 63;
  int node = blockIdx.x * 4 + wave;                 // 12500*4 = 50000 exact
  int c0 = lane * 4;
  float4 a = gather_node(hn8, rowptr, csr, node, c0);
  float di = dinv[node];
  float4 b = *(const float4*)(bias + c0);
  sm[wave * 256 + c0 + 0] = fmaxf(fmaf(di, a.x, b.x), 0.f);
  sm[wave * 256 + c0 + 1] = fmaxf(fmaf(di, a.y, b.y), 0.f);
  sm[wave * 256 + c0 + 2] = fmaxf(fmaf(di, a.z, b.z), 0.f);
  sm[wave * 256 + c0 + 3] = fmaxf(fmaf(di, a.w, b.w), 0.f);
  __syncthreads();
  int t = threadIdx.x;
  partials[(size_t)blockIdx.x * 256 + t] = sm[t] + sm[256 + t] + sm[512 + t] + sm[768 + t];
}

// ---------------- readout ----------------
__global__ __launch_bounds__(256) void reduce2_kernel(const float* __restrict__ partials,
                                                      float* __restrict__ p2) {
  int t = threadIdx.x, b = blockIdx.x;              // 64 blocks
  float s = 0.f;
  for (int r = b; r < AGG_BLOCKS; r += RED_BLOCKS) s += partials[(size_t)r * 256 + t];
  p2[b * 256 + t] = s;
}
__global__ __launch_bounds__(256) void final_kernel(const float* __restrict__ p2,
                                                    const float* __restrict__ Wfc,
                                                    const float* __restrict__ bfc,
                                                    float* __restrict__ out) {
  __shared__ float red[256];
  int t = threadIdx.x;
  float s = 0.f;
  for (int b = 0; b < RED_BLOCKS; ++b) s += p2[b * 256 + t];
  float g = s * (1.0f / (float)NODES);
  red[t] = g * Wfc[t];
  __syncthreads();
  for (int off = 128; off > 0; off >>= 1) {
    if (t < off) red[t] += red[t + off];
    __syncthreads();
  }
  if (t == 0) {
    float z = red[0] + bfc[0];
    out[0] = 1.0f / (1.0f + expf(-z));
  }
}

// ---------------- launch ----------------
extern "C" void kernel_launch(void* const* d_in, const int* in_sizes, int n_in,
                              void* d_out, int out_size, void* d_ws, size_t ws_size,
                              hipStream_t stream) {
  (void)in_sizes; (void)n_in; (void)out_size; (void)ws_size;
  const float* x   = (const float*)d_in[0];
  const int*   ei  = (const int*)d_in[1];
  const float* W1  = (const float*)d_in[2];
  const float* b1  = (const float*)d_in[3];
  const float* W2  = (const float*)d_in[4];
  const float* b2  = (const float*)d_in[5];
  const float* Wfc = (const float*)d_in[6];
  const float* bfc = (const float*)d_in[7];
  float* out = (float*)d_out;
  char* ws = (char*)d_ws;

  unsigned char*  hn8  = (unsigned char*)(ws + OFF_HN);
  unsigned char*  x8   = (unsigned char*)(ws + OFF_H1P);   // x8 aliases h1p region
  unsigned char*  h1p8 = (unsigned char*)(ws + OFF_H1P);   // written after gemm1
  unsigned char*  w1t8 = (unsigned char*)(ws + OFF_W1T);
  unsigned char*  w2t8 = (unsigned char*)(ws + OFF_W2T);
  int*   deg    = (int*)(ws + OFF_DEG);
  int*   fill   = (int*)(ws + OFF_FILL);
  int*   rowptr = (int*)(ws + OFF_ROWP);
  int*   csr    = (int*)(ws + OFF_CSR);
  int*   bsum   = (int*)(ws + OFF_BSUM);
  int*   boff   = (int*)(ws + OFF_BOFF);
  float* part   = (float*)(ws + OFF_PART);
  float* p2     = (float*)(ws + OFF_P2);
  float* dinv   = (float*)(ws + OFF_DINV);

  transw8_zero_kernel<<<866, 256, 0, stream>>>(W1, W2, w1t8, w2t8, (int4*)deg);
  hist_kernel<<<EDGES / 256, 256, 0, stream>>>(ei, deg);
  scan1_kernel<<<NB_SCAN, 256, 0, stream>>>(deg, rowptr, bsum, dinv);
  scan2_kernel<<<1, 256, 0, stream>>>(bsum, boff, rowptr + NODES);
  scan3_kernel<<<NB_SCAN, 256, 0, stream>>>(rowptr, boff);
  fill_kernel<<<EDGES / 256, 256, 0, stream>>>(ei, rowptr, fill, csr);
  convx8_kernel<<<NODES * INDIM / (256 * 8), 256, 0, stream>>>(x, x8);

  gemm_fp8_kernel<INDIM><<<GEMM_MB256, 512, 0, stream>>>(x8, w1t8, dinv, hn8);
  agg1_kernel<<<AGG_BLOCKS, 256, 0, stream>>>(hn8, dinv, rowptr, csr, b1, h1p8);
  gemm_fp8_kernel<HIDDIM><<<GEMM_MB256, 512, 0, stream>>>(h1p8, w2t8, dinv, hn8);
  agg2_kernel<<<AGG_BLOCKS, 256, 0, stream>>>(hn8, dinv, rowptr, csr, b2, part);
  reduce2_kernel<<<RED_BLOCKS, 256, 0, stream>>>(part, p2);
  final_kernel<<<1, 256, 0, stream>>>(p2, Wfc, bfc, out);
}